// Round 4
// baseline (306.978 us; speedup 1.0000x reference)
//
#include <hip/hip_runtime.h>
#include <stdint.h>

typedef unsigned short ushort_t;
typedef __bf16 bf16x8 __attribute__((ext_vector_type(8)));
typedef float f32x4 __attribute__((ext_vector_type(4)));
typedef ushort_t us4 __attribute__((ext_vector_type(4)));

#define MFMA16(a, b, c) __builtin_amdgcn_mfma_f32_16x16x32_bf16((a), (b), (c), 0, 0, 0)

constexpr int Bn = 4, Sn = 2048, Dn = 1024, Hn = 16, HDn = 64;
constexpr float SCALE = 0.125f;   // 1/sqrt(64)
constexpr float NEG = -1e9f;

__device__ __forceinline__ float bf2f(ushort_t u) {
  unsigned x = ((unsigned)u) << 16;
  return __builtin_bit_cast(float, x);
}
__device__ __forceinline__ ushort_t f2bf(float f) {
  unsigned x = __builtin_bit_cast(unsigned, f);
  x = x + 0x7FFFu + ((x >> 16) & 1u);   // RNE
  return (ushort_t)(x >> 16);
}
// 8 x f32 -> bf16x8 via compiler (v_cvt_pk_bf16_f32, RNE — same bits as f2bf)
__device__ __forceinline__ bf16x8 cvt8(f32x4 a, f32x4 b) {
  bf16x8 r;
  r[0] = (__bf16)a[0]; r[1] = (__bf16)a[1]; r[2] = (__bf16)a[2]; r[3] = (__bf16)a[3];
  r[4] = (__bf16)b[0]; r[5] = (__bf16)b[1]; r[6] = (__bf16)b[2]; r[7] = (__bf16)b[3];
  return r;
}
__device__ __forceinline__ uint4 ld8_f32_bf16(const float* __restrict__ p) {
  float4 a = *(const float4*)p;
  float4 b = *(const float4*)(p + 4);
  union { ushort_t u[8]; uint4 v; } r;
  r.u[0] = f2bf(a.x); r.u[1] = f2bf(a.y); r.u[2] = f2bf(a.z); r.u[3] = f2bf(a.w);
  r.u[4] = f2bf(b.x); r.u[5] = f2bf(b.y); r.u[6] = f2bf(b.z); r.u[7] = f2bf(b.w);
  return r.v;
}
// async global->LDS, 16B per lane; LDS dest = wave-uniform base + lane*16
__device__ __forceinline__ void gl2lds16(const void* g, void* l) {
  __builtin_amdgcn_global_load_lds(
      (__attribute__((address_space(1))) void*)g,
      (__attribute__((address_space(3))) void*)l, 16, 0, 0);
}

// Weights-only f32->bf16 (X is now consumed as f32 directly by gemm_qkv).
// 4 W x 1048576 elems; 512 blocks each = 2048 blocks.
__global__ __launch_bounds__(256)
void cvt_w(const float* __restrict__ wq, const float* __restrict__ wk,
           const float* __restrict__ wv, const float* __restrict__ wo,
           ushort_t* __restrict__ Wd) {
  const int wb = blockIdx.x, which = wb >> 9;
  const float* s = which == 0 ? wq : which == 1 ? wk : which == 2 ? wv : wo;
  size_t i = ((size_t)(wb & 511) * 256 + threadIdx.x) * 8;
  *(uint4*)(Wd + (size_t)which * 1048576 + i) = ld8_f32_bf16(s + i);
}

// Fused Q/K/V projections, f32 A-operand staged directly (no pre-pass).
// A-tile lives in LDS as f32 [128][64] with 16-slot XOR swizzle
// (granule slot = p ^ (row&15), granule = 4 floats): gl2lds source walk is
// coalesced per row and the ds_read_b128 pattern hits 8 distinct 16B
// granules / 32 banks per instruction (same structure as the bf16 path).
// Conversion to bf16 happens at fragment read (v_cvt_pk_bf16_f32, RNE).
// z = 0/1/2 selects X, W, bias, dst, epilogue.
__global__ __launch_bounds__(256, 4)
void gemm_qkv(const float* __restrict__ xq, const float* __restrict__ xk,
              const float* __restrict__ xv, const ushort_t* __restrict__ Wb,
              const float* __restrict__ bq, const float* __restrict__ bk,
              const float* __restrict__ bv, ushort_t* __restrict__ Qd,
              ushort_t* __restrict__ Ktd, ushort_t* __restrict__ Vtd) {
  constexpr int K = 1024;
  __shared__ __align__(16) float    Asf[128 * 64];   // 32 KB f32 A-tile
  __shared__ __align__(16) ushort_t Bs[128 * 64];    // 16 KB bf16 B-tile

  const int z = blockIdx.z;
  const float* A = z == 0 ? xq : z == 1 ? xk : xv;
  const ushort_t* Wt = Wb + (size_t)z * 1048576;
  const float* bias = z == 0 ? bq : z == 1 ? bk : bv;
  ushort_t* Cp = z == 0 ? Qd : z == 1 ? Ktd : Vtd;

  const int tid = threadIdx.x;
  const int lane = tid & 63, w = tid >> 6;
  const int quad = lane >> 4, l16 = lane & 15;
  const int wm = w >> 1, wn = w & 1;
  const int row0 = blockIdx.x * 128;   // x = row (XCD co-location)
  const int col0 = blockIdx.y * 128;   // y = col

  const int sr = lane >> 3;
  const int sg = ((lane & 7) ^ (sr & 7)) * 8;
  const ushort_t* Bb = Wt + (size_t)(col0 + w * 32 + sr) * K + sg;

  // A staging: lane covers row (w*32 + i*4 + (lane>>4)), granule slot lane&15
  const int rq4 = lane >> 4;           // row within 4-row region
  const int gsl = lane & 15;           // LDS granule slot

  f32x4 acc[4][4] = {};

  for (int k0 = 0; k0 < K; k0 += 64) {
    __syncthreads();
#pragma unroll
    for (int i = 0; i < 4; ++i)
      gl2lds16(Bb + (size_t)(i * 8) * K + k0, &Bs[(w * 32 + i * 8) * 64]);
#pragma unroll
    for (int i = 0; i < 8; ++i) {
      const int lr4 = w * 32 + i * 4;            // region base row
      const int lr = lr4 + rq4;                  // this lane's row
      const int psrc = gsl ^ (lr & 15);          // source granule
      gl2lds16(A + (size_t)(row0 + lr) * K + k0 + (psrc << 2), &Asf[lr4 * 64]);
    }
    __syncthreads();
#pragma unroll
    for (int ks = 0; ks < 2; ++ks) {
      const int kg = ((ks * 4 + quad) ^ (l16 & 7)) * 8;
      const int p0 = (ks * 4 + quad) * 2;
      const int s0 = ((p0 ^ l16) << 2), s1 = (((p0 ^ l16) ^ 1) << 2);
      bf16x8 af[4], bfr[4];
#pragma unroll
      for (int mt = 0; mt < 4; ++mt) {
        const int rb = (wm * 64 + mt * 16 + l16) * 64;
        af[mt] = cvt8(*(const f32x4*)(&Asf[rb + s0]),
                      *(const f32x4*)(&Asf[rb + s1]));
      }
#pragma unroll
      for (int nt = 0; nt < 4; ++nt)
        bfr[nt] = *(const bf16x8*)(&Bs[(wn * 64 + nt * 16 + l16) * 64 + kg]);
#pragma unroll
      for (int mt = 0; mt < 4; ++mt)
#pragma unroll
        for (int nt = 0; nt < 4; ++nt)
          acc[mt][nt] = MFMA16(af[mt], bfr[nt], acc[mt][nt]);
    }
  }

#pragma unroll
  for (int mt = 0; mt < 4; ++mt) {
#pragma unroll
    for (int nt = 0; nt < 4; ++nt) {
      const int col = col0 + wn * 64 + nt * 16 + l16;
      const float bv4 = bias[col];
      const int rowb = row0 + wm * 64 + mt * 16 + quad * 4;
      if (z != 0) {          // transposed scatter: [b,h,hd,s], b64 over s
        const int b = rowb >> 11, s = rowb & (Sn - 1);
        const int h = col >> 6, hd = col & 63;
        us4 pk;
#pragma unroll
        for (int r = 0; r < 4; ++r) pk[r] = f2bf(acc[mt][nt][r] + bv4);
        *(us4*)(Cp + ((size_t)((b * Hn + h) * HDn + hd)) * Sn + s) = pk;
      } else {               // Q scatter: [b,h,s,hd]
#pragma unroll
        for (int r = 0; r < 4; ++r) {
          const int row = rowb + r;
          const int b = row >> 11, s = row & (Sn - 1);
          const int h = col >> 6, hd = col & 63;
          Cp[(((size_t)(b * Hn + h) * Sn + s) << 6) + hd] = f2bf(acc[mt][nt][r] + bv4);
        }
      }
    }
  }
}

// Final projection: C[M,N] f32 = A[M,K]bf16 @ W[N,K]^T + bias.
__global__ __launch_bounds__(256, 4)
void gemm_out(const ushort_t* __restrict__ A, const ushort_t* __restrict__ Wt,
              const float* __restrict__ bias, float* __restrict__ Cp) {
  constexpr int K = 1024;
  __shared__ __align__(16) ushort_t As[128 * 64];
  __shared__ __align__(16) ushort_t Bs[128 * 64];

  const int tid = threadIdx.x;
  const int lane = tid & 63, w = tid >> 6;
  const int quad = lane >> 4, l16 = lane & 15;
  const int wm = w >> 1, wn = w & 1;
  const int row0 = blockIdx.x * 128;
  const int col0 = blockIdx.y * 128;

  const int sr = lane >> 3;
  const int sg = ((lane & 7) ^ (sr & 7)) * 8;
  const ushort_t* Ab = A  + (size_t)(row0 + w * 32 + sr) * K + sg;
  const ushort_t* Bb = Wt + (size_t)(col0 + w * 32 + sr) * K + sg;

  f32x4 acc[4][4] = {};

  for (int k0 = 0; k0 < K; k0 += 64) {
    __syncthreads();
#pragma unroll
    for (int i = 0; i < 4; ++i) {
      gl2lds16(Ab + (size_t)(i * 8) * K + k0, &As[(w * 32 + i * 8) * 64]);
      gl2lds16(Bb + (size_t)(i * 8) * K + k0, &Bs[(w * 32 + i * 8) * 64]);
    }
    __syncthreads();
#pragma unroll
    for (int ks = 0; ks < 2; ++ks) {
      const int kg = ((ks * 4 + quad) ^ (l16 & 7)) * 8;
      bf16x8 af[4], bfr[4];
#pragma unroll
      for (int mt = 0; mt < 4; ++mt)
        af[mt] = *(const bf16x8*)(&As[(wm * 64 + mt * 16 + l16) * 64 + kg]);
#pragma unroll
      for (int nt = 0; nt < 4; ++nt)
        bfr[nt] = *(const bf16x8*)(&Bs[(wn * 64 + nt * 16 + l16) * 64 + kg]);
#pragma unroll
      for (int mt = 0; mt < 4; ++mt)
#pragma unroll
        for (int nt = 0; nt < 4; ++nt)
          acc[mt][nt] = MFMA16(af[mt], bfr[nt], acc[mt][nt]);
    }
  }

#pragma unroll
  for (int mt = 0; mt < 4; ++mt)
#pragma unroll
    for (int nt = 0; nt < 4; ++nt) {
      const int col = col0 + wn * 64 + nt * 16 + l16;
      const float bv = bias[col];
      const int rowb = row0 + wm * 64 + mt * 16 + quad * 4;
#pragma unroll
      for (int r = 0; r < 4; ++r)
        Cp[(size_t)(rowb + r) * 1024 + col] = acc[mt][nt][r] + bv;
    }
}

// Per-tile outer products, fully parallel:
// G_t[n_v][d_k] = sum_{k in tile t} K[k][d_k]*V[k][n_v]  (f32),
// R[bh][t][n] = sum_{k in tile t} V[k][n]                (f32).
__global__ __launch_bounds__(256)
void gtile(const ushort_t* __restrict__ Kt, const ushort_t* __restrict__ Vt,
           float* __restrict__ Gd, float* __restrict__ Rs) {
  __shared__ __align__(16) ushort_t Kts[4096];
  __shared__ __align__(16) ushort_t Vts[4096];
  __shared__ float tsum[64];
  const int tid = threadIdx.x, lane = tid & 63, w = tid >> 6;
  const int quad = lane >> 4, l16 = lane & 15;
  const int t = blockIdx.x, bh = blockIdx.y;
  const ushort_t* Ktb = Kt + (size_t)bh * HDn * Sn;
  const ushort_t* Vtb = Vt + (size_t)bh * HDn * Sn;

  const int sr = lane >> 3;
  const int sg = ((lane & 7) ^ (sr & 7)) * 8;

  if (tid < 64) tsum[tid] = 0.f;
#pragma unroll
  for (int c = 0; c < 2; ++c) {
    const int row = w * 16 + c * 8;
    gl2lds16(Ktb + (size_t)(row + sr) * Sn + t * 64 + sg, &Kts[row * 64]);
    gl2lds16(Vtb + (size_t)(row + sr) * Sn + t * 64 + sg, &Vts[row * 64]);
  }
  __syncthreads();

  f32x4 zacc[4] = {};
#pragma unroll
  for (int ks = 0; ks < 2; ++ks) {
    const int kg = ((ks * 4 + quad) ^ (l16 & 7)) * 8;
    bf16x8 ak = *(const bf16x8*)(&Kts[(w * 16 + l16) * 64 + kg]);
#pragma unroll
    for (int nt = 0; nt < 4; ++nt) {
      bf16x8 bv8 = *(const bf16x8*)(&Vts[(nt * 16 + l16) * 64 + kg]);
      zacc[nt] = MFMA16(ak, bv8, zacc[nt]);
    }
  }
  float* gd = Gd + (size_t)(bh * 32 + t) * 4096;
#pragma unroll
  for (int nt = 0; nt < 4; ++nt)
    *(f32x4*)(gd + (nt * 16 + l16) * 64 + w * 16 + quad * 4) = zacc[nt];

  // V row partial sums: thread (n = tid&63, j = tid>>6)
  {
    const int n = tid & 63, j = tid >> 6;
    float p = 0.f;
#pragma unroll
    for (int gg2 = 0; gg2 < 2; ++gg2) {
      const int g = 2 * j + gg2;
      union { uint4 v; ushort_t u[8]; } c;
      c.v = *(const uint4*)(&Vts[n * 64 + ((g ^ (n & 7)) << 3)]);
#pragma unroll
      for (int e = 0; e < 8; ++e) p += bf2f(c.u[e]);
    }
    atomicAdd(&tsum[n], p);
  }
  __syncthreads();
  if (tid < 64) Rs[(size_t)(bh * 32 + t) * 64 + tid] = tsum[tid];
}

// Fused prefix-scan + attention. Grid (x=bh 64, y=group 8); block (bh,g)
// owns q-tiles qt = 4g..4g+3.  Z never touches HBM: register prefix over
// G (ascending-t f32 => identical numerics to the old scanz), written
// straight into the swizzled LDS layout the MFMA reads. suffV computed
// locally from R. Same-bh blocks at stride 64 -> same XCD L2.
__global__ __launch_bounds__(256)
void scan_attn(const ushort_t* __restrict__ Q, const ushort_t* __restrict__ Kt,
               const ushort_t* __restrict__ Vt, const float* __restrict__ Gd,
               const float* __restrict__ Rs, ushort_t* __restrict__ O) {
  __shared__ __align__(16) ushort_t Vts[2][4096];
  __shared__ __align__(16) ushort_t Zs[4096];
  __shared__ __align__(16) ushort_t Ks[4096];
  __shared__ __align__(16) ushort_t Ss[64][72];
  __shared__ __align__(16) float sfx[4][64];

  const int tid = threadIdx.x, lane = tid & 63, w = tid >> 6;
  const int quad = lane >> 4, l16 = lane & 15;
  const int bh = blockIdx.x;           // 0..63
  const int g = blockIdx.y;            // 0..7, tiles 4g..4g+3
  const int qt0 = g * 4;
  const int b = bh >> 4, h = bh & 15;
  const ushort_t* Qb  = Q  + (size_t)bh * Sn * HDn;
  const ushort_t* Ktb = Kt + (size_t)bh * HDn * Sn;
  const ushort_t* Vtb = Vt + (size_t)bh * HDn * Sn;
  const float* Gb = Gd + (size_t)bh * 32 * 4096;
  const float* Rb = Rs + (size_t)bh * 32 * 64;

  const int sr = lane >> 3;
  const int sg = ((lane & 7) ^ (sr & 7)) * 8;
  const int q8 = lane & 7, h8 = lane >> 3;

  // Z ownership: thread -> row n = tid>>2 (0..63), cols [zd0, zd0+16)
  const int zn = tid >> 2, zd0 = (tid & 3) * 16;
  const float* gthr = Gb + zn * 64 + zd0;

  uint4  kvr[2][2];
  bf16x8 bqr[2][2];
  f32x4  gq[2][4];

  // prologue: issue all tile-qt0 loads (fly under sfx + prefix stream)
  {
    const int q0 = qt0 * 64;
#pragma unroll
    for (int c = 0; c < 2; ++c) {
      const int row = w * 16 + c * 8;
      gl2lds16(Vtb + (size_t)(row + sr) * Sn + q0 + sg, &Vts[0][row * 64]);
      kvr[0][c] = *(const uint4*)(Ktb + (size_t)(w * 16 + c * 8 + h8) * Sn + q0 + q8 * 8);
    }
#pragma unroll
    for (int ks = 0; ks < 2; ++ks)
      bqr[0][ks] = *(const bf16x8*)(Qb + (size_t)(q0 + w * 16 + l16) * HDn + (ks * 4 + quad) * 8);
#pragma unroll
    for (int j = 0; j < 4; ++j)
      gq[0][j] = *(const f32x4*)(gthr + (size_t)qt0 * 4096 + 4 * j);
  }

  // local suffix-V: sfx[i][n] = sum_{tau > qt0+i} R[tau][n]
  if (tid < 64) {
    float acc = 0.f;
    for (int tau = 31; tau >= qt0; --tau) {
      if (tau < qt0 + 4) sfx[tau - qt0][tid] = acc;
      acc += Rb[(size_t)tau * 64 + tid];
    }
  }

  // register prefix: Zacc = sum_{tau < qt0} G_tau   (ascending, f32)
  f32x4 Zacc[4] = {};
#pragma unroll 4
  for (int tau = 0; tau < qt0; ++tau) {
#pragma unroll
    for (int j = 0; j < 4; ++j)
      Zacc[j] += *(const f32x4*)(gthr + (size_t)tau * 4096 + 4 * j);
  }

#pragma unroll 4
  for (int i = 0; i < 4; ++i) {
    const int cur = i & 1;
    const int qt = qt0 + i, q0 = qt * 64;

    __syncthreads();   // B1: compute i-1 done (Zs/Ks free); i=0: sfx cover

    // write Z for this q-tile from regs into swizzled LDS layout
#pragma unroll
    for (int j = 0; j < 4; ++j) {
      const int d = zd0 + 4 * j;
      us4 pk;
#pragma unroll
      for (int r = 0; r < 4; ++r) pk[r] = f2bf(SCALE * Zacc[j][r]);
      *(us4*)(&Zs[zn * 64 + (((d >> 3) ^ (zn & 7)) << 3) + (d & 7)]) = pk;
    }
    // transpose-write diagonal K tile (regs -> Ks, rotated+swizzled)
#pragma unroll
    for (int c = 0; c < 2; ++c) {
      const int hd = w * 16 + c * 8 + h8;
      const int G = hd >> 3;
      const ushort_t* ku = (const ushort_t*)&kvr[cur][c];
#pragma unroll
      for (int j = 0; j < 8; ++j) {
        const int e = (j + q8) & 7;
        const int s = q8 * 8 + e;
        Ks[s * 64 + ((G ^ e) << 3) + (hd & 7)] = ku[e];
      }
    }

    __syncthreads();   // B2: ds_writes visible + V(qt) staging drained

    if (i < 3) {       // issue next-tile loads; fly under compute(i)
      const int q1 = (qt + 1) * 64, nxt = 1 - cur;
#pragma unroll
      for (int c = 0; c < 2; ++c) {
        const int row = w * 16 + c * 8;
        gl2lds16(Vtb + (size_t)(row + sr) * Sn + q1 + sg, &Vts[nxt][row * 64]);
        kvr[nxt][c] = *(const uint4*)(Ktb + (size_t)(w * 16 + c * 8 + h8) * Sn + q1 + q8 * 8);
      }
#pragma unroll
      for (int ks = 0; ks < 2; ++ks)
        bqr[nxt][ks] = *(const bf16x8*)(Qb + (size_t)(q1 + w * 16 + l16) * HDn + (ks * 4 + quad) * 8);
#pragma unroll
      for (int j = 0; j < 4; ++j)
        gq[nxt][j] = *(const f32x4*)(gthr + (size_t)(qt + 1) * 4096 + 4 * j);
    }

    // ---- compute q-tile qt ----
    f32x4 oacc[4] = {};
#pragma unroll
    for (int ks = 0; ks < 2; ++ks) {        // prefix: O^T += Z' · Q^T
      const int kg = ((ks * 4 + quad) ^ (l16 & 7)) * 8;
#pragma unroll
      for (int nt = 0; nt < 4; ++nt) {
        bf16x8 az = *(const bf16x8*)(&Zs[(nt * 16 + l16) * 64 + kg]);
        oacc[nt] = MFMA16(az, bqr[cur][ks], oacc[nt]);
      }
    }
    f32x4 sacc[4] = {};
#pragma unroll
    for (int ks = 0; ks < 2; ++ks) {        // diagonal: S^T = K_d · Q^T
      const int kg = ((ks * 4 + quad) ^ (l16 & 7)) * 8;
#pragma unroll
      for (int nt = 0; nt < 4; ++nt) {
        bf16x8 ak = *(const bf16x8*)(&Ks[(nt * 16 + l16) * 64 + kg]);
        sacc[nt] = MFMA16(ak, bqr[cur][ks], sacc[nt]);
      }
    }
    const int qrel = w * 16 + l16;          // mask + scale -> Ss (b64, intra-wave)
#pragma unroll
    for (int nt = 0; nt < 4; ++nt) {
      const int kb = nt * 16 + quad * 4;
      us4 pk;
#pragma unroll
      for (int r = 0; r < 4; ++r) {
        float val = (kb + r > qrel) ? NEG : sacc[nt][r] * SCALE;
        pk[r] = f2bf(val);
      }
      *(us4*)(&Ss[qrel][kb]) = pk;
    }
#pragma unroll
    for (int ks = 0; ks < 2; ++ks) {        // O^T += V_d^T · S_d^T
      bf16x8 bs = *(const bf16x8*)(&Ss[qrel][ks * 32 + quad * 8]);
#pragma unroll
      for (int nt = 0; nt < 4; ++nt) {
        bf16x8 av = *(const bf16x8*)(&Vts[cur][(nt * 16 + l16) * 64 + (((ks * 4 + quad) ^ (l16 & 7)) << 3)]);
        oacc[nt] = MFMA16(av, bs, oacc[nt]);
      }
    }

    // masked tail + store O[b,s,d] (b64 over n)
    const int s = q0 + w * 16 + l16;
#pragma unroll
    for (int nt = 0; nt < 4; ++nt) {
      const int nb = nt * 16 + quad * 4;
      float4 s4 = *(const float4*)(&sfx[i][nb]);
      us4 pk;
      pk[0] = f2bf(oacc[nt][0] + NEG * s4.x);
      pk[1] = f2bf(oacc[nt][1] + NEG * s4.y);
      pk[2] = f2bf(oacc[nt][2] + NEG * s4.z);
      pk[3] = f2bf(oacc[nt][3] + NEG * s4.w);
      *(us4*)(&O[((size_t)(b * Sn + s)) * Dn + h * 64 + nb]) = pk;
    }

    // advance prefix: Zacc += G_qt (loads issued one iteration ago)
#pragma unroll
    for (int j = 0; j < 4; ++j) Zacc[j] += gq[cur][j];
  }
}

extern "C" void kernel_launch(void* const* d_in, const int* in_sizes, int n_in,
                              void* d_out, int out_size, void* d_ws, size_t ws_size,
                              hipStream_t stream) {
  const float* Xq = (const float*)d_in[0];
  const float* Xk = (const float*)d_in[1];
  const float* Xv = (const float*)d_in[2];
  // d_in[3]: causal mask (int32) — tril, handled analytically
  const float* Wq = (const float*)d_in[4];
  const float* bq = (const float*)d_in[5];
  const float* Wk = (const float*)d_in[6];
  const float* bk = (const float*)d_in[7];
  const float* Wv = (const float*)d_in[8];
  const float* bv = (const float*)d_in[9];
  const float* Wo = (const float*)d_in[10];
  const float* bo = (const float*)d_in[11];

  // ws (MiB): [48,56) Wb(4) | [56,72) Q | [72,88) Kt | [88,104) Vt |
  // [120,136) O | [144,176) G f32 | [176,176.5) R f32
  constexpr size_t MiB = 1024 * 1024;
  char* ws = (char*)d_ws;
  ushort_t* Wb  = (ushort_t*)(ws + 48 * MiB);
  ushort_t* Qb  = (ushort_t*)(ws + 56 * MiB);
  ushort_t* Ktb = (ushort_t*)(ws + 72 * MiB);
  ushort_t* Vtb = (ushort_t*)(ws + 88 * MiB);
  ushort_t* Ob  = (ushort_t*)(ws + 120 * MiB);
  float*    Gd  = (float*)   (ws + 144 * MiB);
  float*    Rsum= (float*)   (ws + 176 * MiB);

  cvt_w<<<2048, 256, 0, stream>>>(Wq, Wk, Wv, Wo, Wb);
  gemm_qkv<<<dim3(64, 8, 3), 256, 0, stream>>>(Xq, Xk, Xv, Wb, bq, bk, bv,
                                               Qb, Ktb, Vtb);
  gtile<<<dim3(32, 64), 256, 0, stream>>>(Ktb, Vtb, Gd, Rsum);
  scan_attn<<<dim3(64, 8), 256, 0, stream>>>(Qb, Ktb, Vtb, Gd, Rsum, Ob);
  gemm_out<<<dim3(64, 8), 256, 0, stream>>>(Ob, Wb + (size_t)3 * 1048576, bo,
                                            (float*)d_out);
}

// Round 5
// 301.032 us; speedup vs baseline: 1.0198x; 1.0198x over previous
//
#include <hip/hip_runtime.h>
#include <stdint.h>

typedef unsigned short ushort_t;
typedef __bf16 bf16x8 __attribute__((ext_vector_type(8)));
typedef float f32x4 __attribute__((ext_vector_type(4)));
typedef ushort_t us4 __attribute__((ext_vector_type(4)));

#define MFMA16(a, b, c) __builtin_amdgcn_mfma_f32_16x16x32_bf16((a), (b), (c), 0, 0, 0)

constexpr int Bn = 4, Sn = 2048, Dn = 1024, Hn = 16, HDn = 64;
constexpr float SCALE = 0.125f;   // 1/sqrt(64)
constexpr float NEG = -1e9f;

__device__ __forceinline__ float bf2f(ushort_t u) {
  unsigned x = ((unsigned)u) << 16;
  return __builtin_bit_cast(float, x);
}
__device__ __forceinline__ ushort_t f2bf(float f) {
  unsigned x = __builtin_bit_cast(unsigned, f);
  x = x + 0x7FFFu + ((x >> 16) & 1u);   // RNE
  return (ushort_t)(x >> 16);
}
// 8 x f32 -> bf16x8 via compiler (v_cvt_pk_bf16_f32, RNE — same bits as f2bf)
__device__ __forceinline__ bf16x8 cvt8(float4 a, float4 b) {
  bf16x8 r;
  r[0] = (__bf16)a.x; r[1] = (__bf16)a.y; r[2] = (__bf16)a.z; r[3] = (__bf16)a.w;
  r[4] = (__bf16)b.x; r[5] = (__bf16)b.y; r[6] = (__bf16)b.z; r[7] = (__bf16)b.w;
  return r;
}
__device__ __forceinline__ uint4 ld8_f32_bf16(const float* __restrict__ p) {
  float4 a = *(const float4*)p;
  float4 b = *(const float4*)(p + 4);
  union { ushort_t u[8]; uint4 v; } r;
  r.u[0] = f2bf(a.x); r.u[1] = f2bf(a.y); r.u[2] = f2bf(a.z); r.u[3] = f2bf(a.w);
  r.u[4] = f2bf(b.x); r.u[5] = f2bf(b.y); r.u[6] = f2bf(b.z); r.u[7] = f2bf(b.w);
  return r.v;
}
// async global->LDS, 16B per lane; LDS dest = wave-uniform base + lane*16
__device__ __forceinline__ void gl2lds16(const void* g, void* l) {
  __builtin_amdgcn_global_load_lds(
      (__attribute__((address_space(1))) void*)g,
      (__attribute__((address_space(3))) void*)l, 16, 0, 0);
}

// Weights-only f32->bf16 (X is consumed as f32 directly by gemm_qkv).
__global__ __launch_bounds__(256)
void cvt_w(const float* __restrict__ wq, const float* __restrict__ wk,
           const float* __restrict__ wv, const float* __restrict__ wo,
           ushort_t* __restrict__ Wd) {
  const int wb = blockIdx.x, which = wb >> 9;
  const float* s = which == 0 ? wq : which == 1 ? wk : which == 2 ? wv : wo;
  size_t i = ((size_t)(wb & 511) * 256 + threadIdx.x) * 8;
  *(uint4*)(Wd + (size_t)which * 1048576 + i) = ld8_f32_bf16(s + i);
}

// Fused Q/K/V projections, f32 A-operand REG-STAGED (no pre-pass, no f32 LDS):
// per K-step each thread loads 32B f32 of one A-row, converts with
// v_cvt_pk_bf16_f32 and ds_write_b128's into the SAME swizzled bf16 layout
// the r2 kernel used (As[row][g ^ (row&7)] granules) -> read path unchanged,
// staged LDS bytes back to 32 KB/step. Next-step loads are issued before the
// MFMA phase so HBM latency hides under compute (T14).
// z = 0/1/2 selects X, W, bias, dst, epilogue.
__global__ __launch_bounds__(256, 3)
void gemm_qkv(const float* __restrict__ xq, const float* __restrict__ xk,
              const float* __restrict__ xv, const ushort_t* __restrict__ Wb,
              const float* __restrict__ bq, const float* __restrict__ bk,
              const float* __restrict__ bv, ushort_t* __restrict__ Qd,
              ushort_t* __restrict__ Ktd, ushort_t* __restrict__ Vtd) {
  constexpr int K = 1024;
  __shared__ __align__(16) ushort_t As[128 * 64];
  __shared__ __align__(16) ushort_t Bs[128 * 64];

  const int z = blockIdx.z;
  const float* A = z == 0 ? xq : z == 1 ? xk : xv;
  const ushort_t* Wt = Wb + (size_t)z * 1048576;
  const float* bias = z == 0 ? bq : z == 1 ? bk : bv;
  ushort_t* Cp = z == 0 ? Qd : z == 1 ? Ktd : Vtd;

  const int tid = threadIdx.x;
  const int lane = tid & 63, w = tid >> 6;
  const int quad = lane >> 4, l16 = lane & 15;
  const int wm = w >> 1, wn = w & 1;
  const int row0 = blockIdx.x * 128;   // x = row (XCD co-location)
  const int col0 = blockIdx.y * 128;   // y = col

  const int sr = lane >> 3;
  const int sg = ((lane & 7) ^ (sr & 7)) * 8;
  const ushort_t* Bb = Wt + (size_t)(col0 + w * 32 + sr) * K + sg;

  // A reg-staging: lane -> row (w*32 + i*8 + (lane>>3)), f32 cols (lane&7)*8..+8
  // dest slot (lane&7)^(row&7) is lane-constant since i*8 ≡ 0 (mod 8).
  const int ar = lane >> 3;            // row within 8-row group
  const int ac = (lane & 7) * 8;       // f32 elem offset
  const float* Ab = A + (size_t)(row0 + w * 32 + ar) * K + ac;
  ushort_t* Adst = &As[(w * 32 + ar) * 64 + (((lane & 7) ^ (ar & 7)) * 8)];

  float4 a0[4], a1[4];
#pragma unroll
  for (int i = 0; i < 4; ++i) {        // prologue: k0 = 0 loads
    const float* src = Ab + (size_t)(i * 8) * K;
    a0[i] = *(const float4*)src;
    a1[i] = *(const float4*)(src + 4);
  }

  f32x4 acc[4][4] = {};

  for (int k0 = 0; k0 < K; k0 += 64) {
    __syncthreads();                   // LDS free (previous compute done)
#pragma unroll
    for (int i = 0; i < 4; ++i)
      gl2lds16(Bb + (size_t)(i * 8) * K + k0, &Bs[(w * 32 + i * 8) * 64]);
#pragma unroll
    for (int i = 0; i < 4; ++i)
      *(bf16x8*)(Adst + i * 8 * 64) = cvt8(a0[i], a1[i]);
    __syncthreads();                   // ds_writes visible + gl2lds drained

    if (k0 + 64 < K) {                 // next-step A loads fly under compute
#pragma unroll
      for (int i = 0; i < 4; ++i) {
        const float* src = Ab + (size_t)(i * 8) * K + (k0 + 64);
        a0[i] = *(const float4*)src;
        a1[i] = *(const float4*)(src + 4);
      }
    }

#pragma unroll
    for (int ks = 0; ks < 2; ++ks) {
      const int kg = ((ks * 4 + quad) ^ (l16 & 7)) * 8;
      bf16x8 af[4], bfr[4];
#pragma unroll
      for (int mt = 0; mt < 4; ++mt)
        af[mt] = *(const bf16x8*)(&As[(wm * 64 + mt * 16 + l16) * 64 + kg]);
#pragma unroll
      for (int nt = 0; nt < 4; ++nt)
        bfr[nt] = *(const bf16x8*)(&Bs[(wn * 64 + nt * 16 + l16) * 64 + kg]);
#pragma unroll
      for (int mt = 0; mt < 4; ++mt)
#pragma unroll
        for (int nt = 0; nt < 4; ++nt)
          acc[mt][nt] = MFMA16(af[mt], bfr[nt], acc[mt][nt]);
    }
  }

#pragma unroll
  for (int mt = 0; mt < 4; ++mt) {
#pragma unroll
    for (int nt = 0; nt < 4; ++nt) {
      const int col = col0 + wn * 64 + nt * 16 + l16;
      const float bv4 = bias[col];
      const int rowb = row0 + wm * 64 + mt * 16 + quad * 4;
      if (z != 0) {          // transposed scatter: [b,h,hd,s], b64 over s
        const int b = rowb >> 11, s = rowb & (Sn - 1);
        const int h = col >> 6, hd = col & 63;
        us4 pk;
#pragma unroll
        for (int r = 0; r < 4; ++r) pk[r] = f2bf(acc[mt][nt][r] + bv4);
        *(us4*)(Cp + ((size_t)((b * Hn + h) * HDn + hd)) * Sn + s) = pk;
      } else {               // Q scatter: [b,h,s,hd]
#pragma unroll
        for (int r = 0; r < 4; ++r) {
          const int row = rowb + r;
          const int b = row >> 11, s = row & (Sn - 1);
          const int h = col >> 6, hd = col & 63;
          Cp[(((size_t)(b * Hn + h) * Sn + s) << 6) + hd] = f2bf(acc[mt][nt][r] + bv4);
        }
      }
    }
  }
}

// Final projection: C[M,N] f32 = A[M,K]bf16 @ W[N,K]^T + bias.
__global__ __launch_bounds__(256, 4)
void gemm_out(const ushort_t* __restrict__ A, const ushort_t* __restrict__ Wt,
              const float* __restrict__ bias, float* __restrict__ Cp) {
  constexpr int K = 1024;
  __shared__ __align__(16) ushort_t As[128 * 64];
  __shared__ __align__(16) ushort_t Bs[128 * 64];

  const int tid = threadIdx.x;
  const int lane = tid & 63, w = tid >> 6;
  const int quad = lane >> 4, l16 = lane & 15;
  const int wm = w >> 1, wn = w & 1;
  const int row0 = blockIdx.x * 128;
  const int col0 = blockIdx.y * 128;

  const int sr = lane >> 3;
  const int sg = ((lane & 7) ^ (sr & 7)) * 8;
  const ushort_t* Ab = A  + (size_t)(row0 + w * 32 + sr) * K + sg;
  const ushort_t* Bb = Wt + (size_t)(col0 + w * 32 + sr) * K + sg;

  f32x4 acc[4][4] = {};

  for (int k0 = 0; k0 < K; k0 += 64) {
    __syncthreads();
#pragma unroll
    for (int i = 0; i < 4; ++i) {
      gl2lds16(Ab + (size_t)(i * 8) * K + k0, &As[(w * 32 + i * 8) * 64]);
      gl2lds16(Bb + (size_t)(i * 8) * K + k0, &Bs[(w * 32 + i * 8) * 64]);
    }
    __syncthreads();
#pragma unroll
    for (int ks = 0; ks < 2; ++ks) {
      const int kg = ((ks * 4 + quad) ^ (l16 & 7)) * 8;
      bf16x8 af[4], bfr[4];
#pragma unroll
      for (int mt = 0; mt < 4; ++mt)
        af[mt] = *(const bf16x8*)(&As[(wm * 64 + mt * 16 + l16) * 64 + kg]);
#pragma unroll
      for (int nt = 0; nt < 4; ++nt)
        bfr[nt] = *(const bf16x8*)(&Bs[(wn * 64 + nt * 16 + l16) * 64 + kg]);
#pragma unroll
      for (int mt = 0; mt < 4; ++mt)
#pragma unroll
        for (int nt = 0; nt < 4; ++nt)
          acc[mt][nt] = MFMA16(af[mt], bfr[nt], acc[mt][nt]);
    }
  }

#pragma unroll
  for (int mt = 0; mt < 4; ++mt)
#pragma unroll
    for (int nt = 0; nt < 4; ++nt) {
      const int col = col0 + wn * 64 + nt * 16 + l16;
      const float bv = bias[col];
      const int rowb = row0 + wm * 64 + mt * 16 + quad * 4;
#pragma unroll
      for (int r = 0; r < 4; ++r)
        Cp[(size_t)(rowb + r) * 1024 + col] = acc[mt][nt][r] + bv;
    }
}

// Per-tile outer products. Grid SWAPPED to (x=bh 64, y=t 32) so a G[bh] slice
// is written on XCD (bh mod 8) — the same XCD scan_attn reads it from
// (scan_attn block id = bh + 64g ≡ bh mod 8). Previously writer XCD was
// (t mod 8): every G read crossed XCDs (L2 miss -> IC).
__global__ __launch_bounds__(256)
void gtile(const ushort_t* __restrict__ Kt, const ushort_t* __restrict__ Vt,
           float* __restrict__ Gd, float* __restrict__ Rs) {
  __shared__ __align__(16) ushort_t Kts[4096];
  __shared__ __align__(16) ushort_t Vts[4096];
  __shared__ float tsum[64];
  const int tid = threadIdx.x, lane = tid & 63, w = tid >> 6;
  const int quad = lane >> 4, l16 = lane & 15;
  const int bh = blockIdx.x, t = blockIdx.y;
  const ushort_t* Ktb = Kt + (size_t)bh * HDn * Sn;
  const ushort_t* Vtb = Vt + (size_t)bh * HDn * Sn;

  const int sr = lane >> 3;
  const int sg = ((lane & 7) ^ (sr & 7)) * 8;

  if (tid < 64) tsum[tid] = 0.f;
#pragma unroll
  for (int c = 0; c < 2; ++c) {
    const int row = w * 16 + c * 8;
    gl2lds16(Ktb + (size_t)(row + sr) * Sn + t * 64 + sg, &Kts[row * 64]);
    gl2lds16(Vtb + (size_t)(row + sr) * Sn + t * 64 + sg, &Vts[row * 64]);
  }
  __syncthreads();

  f32x4 zacc[4] = {};
#pragma unroll
  for (int ks = 0; ks < 2; ++ks) {
    const int kg = ((ks * 4 + quad) ^ (l16 & 7)) * 8;
    bf16x8 ak = *(const bf16x8*)(&Kts[(w * 16 + l16) * 64 + kg]);
#pragma unroll
    for (int nt = 0; nt < 4; ++nt) {
      bf16x8 bv8 = *(const bf16x8*)(&Vts[(nt * 16 + l16) * 64 + kg]);
      zacc[nt] = MFMA16(ak, bv8, zacc[nt]);
    }
  }
  float* gd = Gd + (size_t)(bh * 32 + t) * 4096;
#pragma unroll
  for (int nt = 0; nt < 4; ++nt)
    *(f32x4*)(gd + (nt * 16 + l16) * 64 + w * 16 + quad * 4) = zacc[nt];

  // V row partial sums: thread (n = tid&63, j = tid>>6)
  {
    const int n = tid & 63, j = tid >> 6;
    float p = 0.f;
#pragma unroll
    for (int gg2 = 0; gg2 < 2; ++gg2) {
      const int g = 2 * j + gg2;
      union { uint4 v; ushort_t u[8]; } c;
      c.v = *(const uint4*)(&Vts[n * 64 + ((g ^ (n & 7)) << 3)]);
#pragma unroll
      for (int e = 0; e < 8; ++e) p += bf2f(c.u[e]);
    }
    atomicAdd(&tsum[n], p);
  }
  __syncthreads();
  if (tid < 64) Rs[(size_t)(bh * 32 + t) * 64 + tid] = tsum[tid];
}

// Fused prefix-scan + attention. Grid (x=bh 64, y=group 8); block (bh,g)
// owns q-tiles qt = 4g..4g+3.  Z never touches HBM: register prefix over
// G (ascending-t f32), written straight into the swizzled LDS layout the
// MFMA reads. suffV computed locally from R. Same-bh blocks at stride 64
// -> same XCD L2 (now also same XCD as G's writer).
__global__ __launch_bounds__(256)
void scan_attn(const ushort_t* __restrict__ Q, const ushort_t* __restrict__ Kt,
               const ushort_t* __restrict__ Vt, const float* __restrict__ Gd,
               const float* __restrict__ Rs, ushort_t* __restrict__ O) {
  __shared__ __align__(16) ushort_t Vts[2][4096];
  __shared__ __align__(16) ushort_t Zs[4096];
  __shared__ __align__(16) ushort_t Ks[4096];
  __shared__ __align__(16) ushort_t Ss[64][72];
  __shared__ __align__(16) float sfx[4][64];

  const int tid = threadIdx.x, lane = tid & 63, w = tid >> 6;
  const int quad = lane >> 4, l16 = lane & 15;
  const int bh = blockIdx.x;           // 0..63
  const int g = blockIdx.y;            // 0..7, tiles 4g..4g+3
  const int qt0 = g * 4;
  const int b = bh >> 4, h = bh & 15;
  const ushort_t* Qb  = Q  + (size_t)bh * Sn * HDn;
  const ushort_t* Ktb = Kt + (size_t)bh * HDn * Sn;
  const ushort_t* Vtb = Vt + (size_t)bh * HDn * Sn;
  const float* Gb = Gd + (size_t)bh * 32 * 4096;
  const float* Rb = Rs + (size_t)bh * 32 * 64;

  const int sr = lane >> 3;
  const int sg = ((lane & 7) ^ (sr & 7)) * 8;
  const int q8 = lane & 7, h8 = lane >> 3;

  // Z ownership: thread -> row n = tid>>2 (0..63), cols [zd0, zd0+16)
  const int zn = tid >> 2, zd0 = (tid & 3) * 16;
  const float* gthr = Gb + zn * 64 + zd0;

  uint4  kvr[2][2];
  bf16x8 bqr[2][2];
  f32x4  gq[2][4];

  // prologue: issue all tile-qt0 loads (fly under sfx + prefix stream)
  {
    const int q0 = qt0 * 64;
#pragma unroll
    for (int c = 0; c < 2; ++c) {
      const int row = w * 16 + c * 8;
      gl2lds16(Vtb + (size_t)(row + sr) * Sn + q0 + sg, &Vts[0][row * 64]);
      kvr[0][c] = *(const uint4*)(Ktb + (size_t)(w * 16 + c * 8 + h8) * Sn + q0 + q8 * 8);
    }
#pragma unroll
    for (int ks = 0; ks < 2; ++ks)
      bqr[0][ks] = *(const bf16x8*)(Qb + (size_t)(q0 + w * 16 + l16) * HDn + (ks * 4 + quad) * 8);
#pragma unroll
    for (int j = 0; j < 4; ++j)
      gq[0][j] = *(const f32x4*)(gthr + (size_t)qt0 * 4096 + 4 * j);
  }

  // local suffix-V: sfx[i][n] = sum_{tau > qt0+i} R[tau][n]
  if (tid < 64) {
    float acc = 0.f;
    for (int tau = 31; tau >= qt0; --tau) {
      if (tau < qt0 + 4) sfx[tau - qt0][tid] = acc;
      acc += Rb[(size_t)tau * 64 + tid];
    }
  }

  // register prefix: Zacc = sum_{tau < qt0} G_tau   (ascending, f32)
  f32x4 Zacc[4] = {};
#pragma unroll 4
  for (int tau = 0; tau < qt0; ++tau) {
#pragma unroll
    for (int j = 0; j < 4; ++j)
      Zacc[j] += *(const f32x4*)(gthr + (size_t)tau * 4096 + 4 * j);
  }

#pragma unroll 4
  for (int i = 0; i < 4; ++i) {
    const int cur = i & 1;
    const int qt = qt0 + i, q0 = qt * 64;

    __syncthreads();   // B1: compute i-1 done (Zs/Ks free); i=0: sfx cover

    // write Z for this q-tile from regs into swizzled LDS layout
#pragma unroll
    for (int j = 0; j < 4; ++j) {
      const int d = zd0 + 4 * j;
      us4 pk;
#pragma unroll
      for (int r = 0; r < 4; ++r) pk[r] = f2bf(SCALE * Zacc[j][r]);
      *(us4*)(&Zs[zn * 64 + (((d >> 3) ^ (zn & 7)) << 3) + (d & 7)]) = pk;
    }
    // transpose-write diagonal K tile (regs -> Ks, rotated+swizzled)
#pragma unroll
    for (int c = 0; c < 2; ++c) {
      const int hd = w * 16 + c * 8 + h8;
      const int G = hd >> 3;
      const ushort_t* ku = (const ushort_t*)&kvr[cur][c];
#pragma unroll
      for (int j = 0; j < 8; ++j) {
        const int e = (j + q8) & 7;
        const int s = q8 * 8 + e;
        Ks[s * 64 + ((G ^ e) << 3) + (hd & 7)] = ku[e];
      }
    }

    __syncthreads();   // B2: ds_writes visible + V(qt) staging drained

    if (i < 3) {       // issue next-tile loads; fly under compute(i)
      const int q1 = (qt + 1) * 64, nxt = 1 - cur;
#pragma unroll
      for (int c = 0; c < 2; ++c) {
        const int row = w * 16 + c * 8;
        gl2lds16(Vtb + (size_t)(row + sr) * Sn + q1 + sg, &Vts[nxt][row * 64]);
        kvr[nxt][c] = *(const uint4*)(Ktb + (size_t)(w * 16 + c * 8 + h8) * Sn + q1 + q8 * 8);
      }
#pragma unroll
      for (int ks = 0; ks < 2; ++ks)
        bqr[nxt][ks] = *(const bf16x8*)(Qb + (size_t)(q1 + w * 16 + l16) * HDn + (ks * 4 + quad) * 8);
#pragma unroll
      for (int j = 0; j < 4; ++j)
        gq[nxt][j] = *(const f32x4*)(gthr + (size_t)(qt + 1) * 4096 + 4 * j);
    }

    // ---- compute q-tile qt ----
    f32x4 oacc[4] = {};
#pragma unroll
    for (int ks = 0; ks < 2; ++ks) {        // prefix: O^T += Z' · Q^T
      const int kg = ((ks * 4 + quad) ^ (l16 & 7)) * 8;
#pragma unroll
      for (int nt = 0; nt < 4; ++nt) {
        bf16x8 az = *(const bf16x8*)(&Zs[(nt * 16 + l16) * 64 + kg]);
        oacc[nt] = MFMA16(az, bqr[cur][ks], oacc[nt]);
      }
    }
    f32x4 sacc[4] = {};
#pragma unroll
    for (int ks = 0; ks < 2; ++ks) {        // diagonal: S^T = K_d · Q^T
      const int kg = ((ks * 4 + quad) ^ (l16 & 7)) * 8;
#pragma unroll
      for (int nt = 0; nt < 4; ++nt) {
        bf16x8 ak = *(const bf16x8*)(&Ks[(nt * 16 + l16) * 64 + kg]);
        sacc[nt] = MFMA16(ak, bqr[cur][ks], sacc[nt]);
      }
    }
    const int qrel = w * 16 + l16;          // mask + scale -> Ss (b64, intra-wave)
#pragma unroll
    for (int nt = 0; nt < 4; ++nt) {
      const int kb = nt * 16 + quad * 4;
      us4 pk;
#pragma unroll
      for (int r = 0; r < 4; ++r) {
        float val = (kb + r > qrel) ? NEG : sacc[nt][r] * SCALE;
        pk[r] = f2bf(val);
      }
      *(us4*)(&Ss[qrel][kb]) = pk;
    }
#pragma unroll
    for (int ks = 0; ks < 2; ++ks) {        // O^T += V_d^T · S_d^T
      bf16x8 bs = *(const bf16x8*)(&Ss[qrel][ks * 32 + quad * 8]);
#pragma unroll
      for (int nt = 0; nt < 4; ++nt) {
        bf16x8 av = *(const bf16x8*)(&Vts[cur][(nt * 16 + l16) * 64 + (((ks * 4 + quad) ^ (l16 & 7)) << 3)]);
        oacc[nt] = MFMA16(av, bs, oacc[nt]);
      }
    }

    // masked tail + store O[b,s,d] (b64 over n)
    const int s = q0 + w * 16 + l16;
#pragma unroll
    for (int nt = 0; nt < 4; ++nt) {
      const int nb = nt * 16 + quad * 4;
      float4 s4 = *(const float4*)(&sfx[i][nb]);
      us4 pk;
      pk[0] = f2bf(oacc[nt][0] + NEG * s4.x);
      pk[1] = f2bf(oacc[nt][1] + NEG * s4.y);
      pk[2] = f2bf(oacc[nt][2] + NEG * s4.z);
      pk[3] = f2bf(oacc[nt][3] + NEG * s4.w);
      *(us4*)(&O[((size_t)(b * Sn + s)) * Dn + h * 64 + nb]) = pk;
    }

    // advance prefix: Zacc += G_qt (loads issued one iteration ago)
#pragma unroll
    for (int j = 0; j < 4; ++j) Zacc[j] += gq[cur][j];
  }
}

extern "C" void kernel_launch(void* const* d_in, const int* in_sizes, int n_in,
                              void* d_out, int out_size, void* d_ws, size_t ws_size,
                              hipStream_t stream) {
  const float* Xq = (const float*)d_in[0];
  const float* Xk = (const float*)d_in[1];
  const float* Xv = (const float*)d_in[2];
  // d_in[3]: causal mask (int32) — tril, handled analytically
  const float* Wq = (const float*)d_in[4];
  const float* bq = (const float*)d_in[5];
  const float* Wk = (const float*)d_in[6];
  const float* bk = (const float*)d_in[7];
  const float* Wv = (const float*)d_in[8];
  const float* bv = (const float*)d_in[9];
  const float* Wo = (const float*)d_in[10];
  const float* bo = (const float*)d_in[11];

  // ws (MiB): [48,56) Wb(4) | [56,72) Q | [72,88) Kt | [88,104) Vt |
  // [120,136) O | [144,176) G f32 | [176,176.5) R f32
  constexpr size_t MiB = 1024 * 1024;
  char* ws = (char*)d_ws;
  ushort_t* Wb  = (ushort_t*)(ws + 48 * MiB);
  ushort_t* Qb  = (ushort_t*)(ws + 56 * MiB);
  ushort_t* Ktb = (ushort_t*)(ws + 72 * MiB);
  ushort_t* Vtb = (ushort_t*)(ws + 88 * MiB);
  ushort_t* Ob  = (ushort_t*)(ws + 120 * MiB);
  float*    Gd  = (float*)   (ws + 144 * MiB);
  float*    Rsum= (float*)   (ws + 176 * MiB);

  cvt_w<<<2048, 256, 0, stream>>>(Wq, Wk, Wv, Wo, Wb);
  gemm_qkv<<<dim3(64, 8, 3), 256, 0, stream>>>(Xq, Xk, Xv, Wb, bq, bk, bv,
                                               Qb, Ktb, Vtb);
  gtile<<<dim3(64, 32), 256, 0, stream>>>(Ktb, Vtb, Gd, Rsum);
  scan_attn<<<dim3(64, 8), 256, 0, stream>>>(Qb, Ktb, Vtb, Gd, Rsum, Ob);
  gemm_out<<<dim3(64, 8), 256, 0, stream>>>(Ob, Wb + (size_t)3 * 1048576, bo,
                                            (float*)d_out);
}